// Round 5
// baseline (274.645 us; speedup 1.0000x reference)
//
#include <hip/hip_runtime.h>

typedef __attribute__((ext_vector_type(8))) short bf16x8;
typedef __attribute__((ext_vector_type(4))) short bf16x4;
typedef __attribute__((ext_vector_type(4))) float f32x4;

#define L2E 1.44269504088896340736f
#define QSCL 0.18033688011112042f   // 0.125 * log2(e)

__device__ inline unsigned short f2bf(float f) {
  union { float f; unsigned int u; } x; x.f = f;
  return (unsigned short)((x.u + 0x8000u) >> 16);
}
__device__ inline unsigned int f2bf2(float a, float b) {
  union { float f; unsigned int u; } xa, xb;
  xa.f = a; xb.f = b;
  return ((xa.u + 0x8000u) >> 16) | (((xb.u + 0x8000u) & 0xFFFF0000u));
}

__device__ inline void gl_lds16(const void* g, void* l) {
  __builtin_amdgcn_global_load_lds((const __attribute__((address_space(1))) void*)g,
                                   (__attribute__((address_space(3))) void*)l,
                                   16, 0, 0);
}

// Explicit LDS-DMA drain: do NOT rely on the compiler emitting vmcnt(0)
// before s_barrier for global_load_lds (alias-based tracking dropped it in
// R4 -> warm-timing race, post-timing divergence). Cost if redundant: zero.
__device__ inline void vm_drain() {
  asm volatile("s_waitcnt vmcnt(0)" ::: "memory");
}

// ---------------- cast fp32 -> bf16 ----------------
__global__ void cast_bf16_kernel(const float* __restrict__ in,
                                 unsigned short* __restrict__ out, int n4) {
  int i = blockIdx.x * blockDim.x + threadIdx.x;
  int st = gridDim.x * blockDim.x;
  for (; i < n4; i += st) {
    float4 v = reinterpret_cast<const float4*>(in)[i];
    ushort4 o;
    o.x = f2bf(v.x); o.y = f2bf(v.y); o.z = f2bf(v.z); o.w = f2bf(v.w);
    reinterpret_cast<ushort4*>(out)[i] = o;
  }
}

// ---------------- QKV GEMM: [8192,1024] x [3072,1024]^T ----------------
// MODE 0: q/k columns (tn 0..15), swapped-operand MFMA -> C^T, lane holds 4
//         consecutive features at fixed token -> direct b64 stores to [b,h,n,64].
// MODE 1: v columns (tn 16..23), normal MFMA, lane holds 4 consecutive tokens
//         at fixed feature -> direct b64 stores to vT [b,h,64,n].
// sA/sB 16B chunks XOR-swizzled (slot = chunk ^ ((row>>1)&3)) -> 2-way banks.
template <int MODE>
__global__ __launch_bounds__(256, 4) void gemm_qkv_t(
    const unsigned short* __restrict__ A,
    const unsigned short* __restrict__ Bm,
    unsigned short* __restrict__ qo,
    unsigned short* __restrict__ ko,
    unsigned short* __restrict__ vo) {
  __shared__ unsigned short sA[2][128 * 32];
  __shared__ unsigned short sB[2][128 * 32];
  const int K = 1024;
  const int tid = threadIdx.x;
  const int w = tid >> 6, lane = tid & 63;
  const int l15 = lane & 15, quad = lane >> 4;
  const int wm = (w >> 1) * 64, wn = (w & 1) * 64;
  const int tm = blockIdx.y;
  const int tn = (MODE == 0) ? blockIdx.x : blockIdx.x + 16;

  const unsigned short* Ab = A + (size_t)(tm * 128) * K;
  const unsigned short* Bb = Bm + (size_t)(tn * 128) * K;

  const int srow = w * 32 + (lane >> 2);
  const int scol = (((lane & 3) ^ ((lane >> 3) & 3))) * 8;   // swizzled content chunk
  const int rsw = (l15 >> 1) & 3;                            // read-side swizzle key

  const f32x4 fz = {0.f, 0.f, 0.f, 0.f};
  f32x4 acc[4][4];
#pragma unroll
  for (int i = 0; i < 4; i++)
#pragma unroll
    for (int j = 0; j < 4; j++) acc[i][j] = fz;

  gl_lds16(Ab + (size_t)srow * K + scol,        &sA[0][(w * 32) * 32]);
  gl_lds16(Ab + (size_t)(srow + 16) * K + scol, &sA[0][(w * 32 + 16) * 32]);
  gl_lds16(Bb + (size_t)srow * K + scol,        &sB[0][(w * 32) * 32]);
  gl_lds16(Bb + (size_t)(srow + 16) * K + scol, &sB[0][(w * 32 + 16) * 32]);

  int buf = 0;
  for (int k0 = 0; k0 < K; k0 += 32) {
    vm_drain();           // drain prior-iteration (or prologue) LDS-DMA
    __syncthreads();
    if (k0 + 32 < K) {
      int nb = buf ^ 1, kn = k0 + 32;
      gl_lds16(Ab + (size_t)srow * K + kn + scol,        &sA[nb][(w * 32) * 32]);
      gl_lds16(Ab + (size_t)(srow + 16) * K + kn + scol, &sA[nb][(w * 32 + 16) * 32]);
      gl_lds16(Bb + (size_t)srow * K + kn + scol,        &sB[nb][(w * 32) * 32]);
      gl_lds16(Bb + (size_t)(srow + 16) * K + kn + scol, &sB[nb][(w * 32 + 16) * 32]);
    }
    bf16x8 af[4], bfr[4];
#pragma unroll
    for (int mt = 0; mt < 4; mt++)
      af[mt] = *(const bf16x8*)&sA[buf][(wm + mt * 16 + l15) * 32 + ((quad ^ rsw) << 3)];
#pragma unroll
    for (int nt = 0; nt < 4; nt++)
      bfr[nt] = *(const bf16x8*)&sB[buf][(wn + nt * 16 + l15) * 32 + ((quad ^ rsw) << 3)];
#pragma unroll
    for (int mt = 0; mt < 4; mt++)
#pragma unroll
      for (int nt = 0; nt < 4; nt++) {
        if (MODE == 0)
          acc[mt][nt] = __builtin_amdgcn_mfma_f32_16x16x32_bf16(bfr[nt], af[mt], acc[mt][nt], 0, 0, 0);
        else
          acc[mt][nt] = __builtin_amdgcn_mfma_f32_16x16x32_bf16(af[mt], bfr[nt], acc[mt][nt], 0, 0, 0);
      }
    buf ^= 1;
  }

  const int m0 = tm * 128;
  const int bb = m0 >> 10, n0 = m0 & 1023;
  const int cbase = (tn * 128) & 1023;

  if (MODE == 0) {
    const int which = tn >> 3;                 // 0:q 1:k
    const float scl = (which == 0) ? QSCL : 1.0f;
    unsigned short* dst = (which == 0) ? qo : ko;
#pragma unroll
    for (int mt = 0; mt < 4; mt++) {
      int tok = n0 + wm + mt * 16 + l15;
#pragma unroll
      for (int nt = 0; nt < 4; nt++) {
        int c = cbase + wn + nt * 16 + quad * 4;
        int hh = c >> 6, d0 = c & 63;
        uint2 val;
        val.x = f2bf2(acc[mt][nt][0] * scl, acc[mt][nt][1] * scl);
        val.y = f2bf2(acc[mt][nt][2] * scl, acc[mt][nt][3] * scl);
        *(uint2*)&dst[(((size_t)bb * 16 + hh) * 1024 + tok) * 64 + d0] = val;
      }
    }
  } else {
#pragma unroll
    for (int mt = 0; mt < 4; mt++) {
      int tok = n0 + wm + mt * 16 + quad * 4;
#pragma unroll
      for (int nt = 0; nt < 4; nt++) {
        int c = cbase + wn + nt * 16 + l15;
        int hh = c >> 6, dd = c & 63;
        uint2 val;
        val.x = f2bf2(acc[mt][nt][0], acc[mt][nt][1]);
        val.y = f2bf2(acc[mt][nt][2], acc[mt][nt][3]);
        *(uint2*)&vo[(((size_t)bb * 16 + hh) * 64 + dd) * 1024 + tok] = val;
      }
    }
  }
}

// ---------------- flash attention: S^T trick, register PV, dbuf KV ----------------
__global__ __launch_bounds__(256, 4) void attn_kernel(
    const unsigned short* __restrict__ Q,
    const unsigned short* __restrict__ Kg,
    const unsigned short* __restrict__ Vt,
    const float* __restrict__ biases,
    unsigned short* __restrict__ Og) {
  __shared__ unsigned short sK[2][64 * 64];
  __shared__ unsigned short sV[2][64 * 64];   // [d][kv], 16B-chunk XOR-swizzled
  __shared__ float sBias[1024];

  const int bx = blockIdx.x;
  const int bh = bx & 127, qt = bx >> 7;      // XCD swizzle: same bh -> same XCD
  const int h = bh & 15, b = bh >> 4;
  const int tid = threadIdx.x, w = tid >> 6, lane = tid & 63;
  const int l15 = lane & 15, quad = lane >> 4;

  const size_t bhs = (size_t)(b * 16 + h);
  const unsigned short* qbase = Q + (bhs * 1024 + (size_t)qt * 128) * 64;
  const unsigned short* kbase = Kg + bhs * 1024 * 64;
  const unsigned short* vbase = Vt + bhs * 64 * 1024;

  for (int t = tid; t < 1024; t += 256) sBias[t] = biases[h * 1024 + t] * L2E;

  const int sr0 = w * 16 + (lane >> 3);
  const int sc8 = lane & 7;
  const int sw0 = sc8 ^ (lane >> 3);

  gl_lds16(kbase + (size_t)sr0 * 64 + sw0 * 8,        &sK[0][(w * 16) * 64]);
  gl_lds16(kbase + (size_t)(sr0 + 8) * 64 + sw0 * 8,  &sK[0][(w * 16 + 8) * 64]);
  gl_lds16(vbase + (size_t)sr0 * 1024 + sw0 * 8,      &sV[0][(w * 16) * 64]);
  gl_lds16(vbase + (size_t)(sr0 + 8) * 1024 + sw0 * 8,&sV[0][(w * 16 + 8) * 64]);

  bf16x8 qf[2][2];
#pragma unroll
  for (int qb = 0; qb < 2; qb++)
#pragma unroll
    for (int kd = 0; kd < 2; kd++)
      qf[qb][kd] = *(const bf16x8*)(qbase + (w * 32 + qb * 16 + l15) * 64 + kd * 32 + quad * 8);

  const int qg0 = qt * 128 + w * 32;
  int qi[2], qj[2];
#pragma unroll
  for (int qb = 0; qb < 2; qb++) {
    int qr = qg0 + qb * 16 + l15;
    qi[qb] = qr >> 5; qj[qb] = qr & 31;
  }
  const int kvq = quad * 4;

  float rsum[2] = {0.f, 0.f};
  const f32x4 fz = {0.f, 0.f, 0.f, 0.f};
  f32x4 of[2][4];
#pragma unroll
  for (int i = 0; i < 2; i++)
#pragma unroll
    for (int j = 0; j < 4; j++) of[i][j] = fz;

  int buf = 0;
  for (int j0 = 0; j0 < 1024; j0 += 64) {
    vm_drain();           // drain prior-iteration (or prologue) LDS-DMA
    __syncthreads();
    if (j0 + 64 < 1024) {
      int nb = buf ^ 1, jn = j0 + 64;
      gl_lds16(kbase + (size_t)(jn + sr0) * 64 + sw0 * 8,       &sK[nb][(w * 16) * 64]);
      gl_lds16(kbase + (size_t)(jn + sr0 + 8) * 64 + sw0 * 8,   &sK[nb][(w * 16 + 8) * 64]);
      gl_lds16(vbase + (size_t)sr0 * 1024 + jn + sw0 * 8,       &sV[nb][(w * 16) * 64]);
      gl_lds16(vbase + (size_t)(sr0 + 8) * 1024 + jn + sw0 * 8, &sV[nb][(w * 16 + 8) * 64]);
    }
    const unsigned short* K_ = sK[buf];
    const unsigned short* V_ = sV[buf];
    const int j5 = j0 >> 5;

#pragma unroll
    for (int kvb = 0; kvb < 4; kvb++) {
      bf16x8 kf0 = *(const bf16x8*)&K_[(kvb * 16 + l15) * 64 + ((quad ^ (l15 & 7)) << 3)];
      bf16x8 kf1 = *(const bf16x8*)&K_[(kvb * 16 + l15) * 64 + (((4 + quad) ^ (l15 & 7)) << 3)];
      bf16x4 vf[4];
#pragma unroll
      for (int nt = 0; nt < 4; nt++) {
        int d = nt * 16 + l15;
        vf[nt] = *(const bf16x4*)&V_[d * 64 + (((kvb * 2 + (quad >> 1)) ^ (l15 & 7)) << 3) + (quad & 1) * 4];
      }
      const int kvi = j5 + (kvb >> 1);
      const int kvjb = (kvb & 1) * 16 + kvq;
#pragma unroll
      for (int qb = 0; qb < 2; qb++) {
        f32x4 s4 = __builtin_amdgcn_mfma_f32_16x16x32_bf16(kf0, qf[qb][0], fz, 0, 0, 0);
        s4 = __builtin_amdgcn_mfma_f32_16x16x32_bf16(kf1, qf[qb][1], s4, 0, 0, 0);
        const float* bb = sBias + (abs(qi[qb] - kvi) << 5);
        float p0 = __builtin_amdgcn_exp2f(s4.x + bb[abs(qj[qb] - kvjb)]);
        float p1 = __builtin_amdgcn_exp2f(s4.y + bb[abs(qj[qb] - (kvjb + 1))]);
        float p2 = __builtin_amdgcn_exp2f(s4.z + bb[abs(qj[qb] - (kvjb + 2))]);
        float p3 = __builtin_amdgcn_exp2f(s4.w + bb[abs(qj[qb] - (kvjb + 3))]);
        rsum[qb] += (p0 + p1) + (p2 + p3);
        union { unsigned int u[2]; bf16x4 v; } pk;
        pk.u[0] = f2bf2(p0, p1);
        pk.u[1] = f2bf2(p2, p3);
#pragma unroll
        for (int nt = 0; nt < 4; nt++)
          of[qb][nt] = __builtin_amdgcn_mfma_f32_16x16x16bf16_1k(pk.v, vf[nt], of[qb][nt], 0, 0, 0);
      }
    }
    buf ^= 1;
  }

#pragma unroll
  for (int qb = 0; qb < 2; qb++) {
    rsum[qb] += __shfl_xor(rsum[qb], 16);
    rsum[qb] += __shfl_xor(rsum[qb], 32);
  }

#pragma unroll
  for (int qb = 0; qb < 2; qb++)
#pragma unroll
    for (int r = 0; r < 4; r++) {
      float rv = __shfl(rsum[qb], kvq + r, 16);
      float inv = __builtin_amdgcn_rcpf(rv);
      int n = qg0 + qb * 16 + kvq + r;
      size_t orow = ((size_t)b * 1024 + n) * 1024 + h * 64;
#pragma unroll
      for (int nt = 0; nt < 4; nt++)
        Og[orow + nt * 16 + l15] = f2bf(of[qb][nt][r] * inv);
    }
}

// ---------------- out-proj GEMM: [8192,1024] x [1024,1024]^T + b ----------------
__global__ __launch_bounds__(256, 4) void gemm_out_k(
    const unsigned short* __restrict__ A,
    const unsigned short* __restrict__ Bm,
    const float* __restrict__ bias,
    float* __restrict__ out) {
  __shared__ unsigned short sA[2][128 * 32];
  __shared__ unsigned short sB[2][128 * 32];
  const int K = 1024;
  const int tid = threadIdx.x;
  const int w = tid >> 6, lane = tid & 63;
  const int l15 = lane & 15, quad = lane >> 4;
  const int wm = (w >> 1) * 64, wn = (w & 1) * 64;
  const int tm = blockIdx.y, tn = blockIdx.x;

  const unsigned short* Ab = A + (size_t)(tm * 128) * K;
  const unsigned short* Bb = Bm + (size_t)(tn * 128) * K;

  const int srow = w * 32 + (lane >> 2);
  const int scol = (((lane & 3) ^ ((lane >> 3) & 3))) * 8;
  const int rsw = (l15 >> 1) & 3;

  const f32x4 fz = {0.f, 0.f, 0.f, 0.f};
  f32x4 acc[4][4];
#pragma unroll
  for (int i = 0; i < 4; i++)
#pragma unroll
    for (int j = 0; j < 4; j++) acc[i][j] = fz;

  gl_lds16(Ab + (size_t)srow * K + scol,        &sA[0][(w * 32) * 32]);
  gl_lds16(Ab + (size_t)(srow + 16) * K + scol, &sA[0][(w * 32 + 16) * 32]);
  gl_lds16(Bb + (size_t)srow * K + scol,        &sB[0][(w * 32) * 32]);
  gl_lds16(Bb + (size_t)(srow + 16) * K + scol, &sB[0][(w * 32 + 16) * 32]);

  int buf = 0;
  for (int k0 = 0; k0 < K; k0 += 32) {
    vm_drain();           // drain prior-iteration (or prologue) LDS-DMA
    __syncthreads();
    if (k0 + 32 < K) {
      int nb = buf ^ 1, kn = k0 + 32;
      gl_lds16(Ab + (size_t)srow * K + kn + scol,        &sA[nb][(w * 32) * 32]);
      gl_lds16(Ab + (size_t)(srow + 16) * K + kn + scol, &sA[nb][(w * 32 + 16) * 32]);
      gl_lds16(Bb + (size_t)srow * K + kn + scol,        &sB[nb][(w * 32) * 32]);
      gl_lds16(Bb + (size_t)(srow + 16) * K + kn + scol, &sB[nb][(w * 32 + 16) * 32]);
    }
    bf16x8 af[4], bfr[4];
#pragma unroll
    for (int mt = 0; mt < 4; mt++)
      af[mt] = *(const bf16x8*)&sA[buf][(wm + mt * 16 + l15) * 32 + ((quad ^ rsw) << 3)];
#pragma unroll
    for (int nt = 0; nt < 4; nt++)
      bfr[nt] = *(const bf16x8*)&sB[buf][(wn + nt * 16 + l15) * 32 + ((quad ^ rsw) << 3)];
#pragma unroll
    for (int mt = 0; mt < 4; mt++)
#pragma unroll
      for (int nt = 0; nt < 4; nt++)
        acc[mt][nt] = __builtin_amdgcn_mfma_f32_16x16x32_bf16(af[mt], bfr[nt], acc[mt][nt], 0, 0, 0);
    buf ^= 1;
  }

  const int m0 = tm * 128 + wm, c0 = tn * 128 + wn;
#pragma unroll
  for (int mt = 0; mt < 4; mt++)
#pragma unroll
    for (int nt = 0; nt < 4; nt++)
#pragma unroll
      for (int r = 0; r < 4; r++) {
        int m = m0 + mt * 16 + quad * 4 + r;
        int c = c0 + nt * 16 + l15;
        out[(size_t)m * 1024 + c] = acc[mt][nt][r] + bias[c];
      }
}

extern "C" void kernel_launch(void* const* d_in, const int* in_sizes, int n_in,
                              void* d_out, int out_size, void* d_ws, size_t ws_size,
                              hipStream_t stream) {
  const float* x    = (const float*)d_in[0];
  const float* Wqkv = (const float*)d_in[1];
  const float* ab   = (const float*)d_in[2];
  // d_in[3] (bias_idxs) unused: idx == |n/32-m/32|*32 + |n%32-m%32| analytically
  const float* Wout = (const float*)d_in[4];
  const float* bout = (const float*)d_in[5];
  float* out = (float*)d_out;

  char* ws = (char*)d_ws;
  unsigned short* xb  = (unsigned short*)(ws);                    // 16 MB
  unsigned short* wqb = (unsigned short*)(ws + 16777216);         // 6 MB
  unsigned short* wob = (unsigned short*)(ws + 23068672);         // 2 MB
  unsigned short* qw  = (unsigned short*)(ws + 25165824);         // 16 MB
  unsigned short* kw  = (unsigned short*)(ws + 41943040);         // 16 MB
  unsigned short* vw  = (unsigned short*)(ws + 58720256);         // 16 MB (vT)
  unsigned short* ow  = (unsigned short*)(ws + 75497472);         // 16 MB

  cast_bf16_kernel<<<1024, 256, 0, stream>>>(x, xb, 8192 * 1024 / 4);
  cast_bf16_kernel<<<512, 256, 0, stream>>>(Wqkv, wqb, 3072 * 1024 / 4);
  cast_bf16_kernel<<<256, 256, 0, stream>>>(Wout, wob, 1024 * 1024 / 4);
  gemm_qkv_t<0><<<dim3(16, 64), 256, 0, stream>>>(xb, wqb, qw, kw, vw);
  gemm_qkv_t<1><<<dim3(8, 64), 256, 0, stream>>>(xb, wqb, qw, kw, vw);
  attn_kernel<<<1024, 256, 0, stream>>>(qw, kw, vw, ab, ow);
  gemm_out_k<<<dim3(8, 64), 256, 0, stream>>>(ow, wob, bout, out);
}